// Round 1
// baseline (2499.312 us; speedup 1.0000x reference)
//
#include <hip/hip_runtime.h>

#define T_TOK 8192
#define F_IN  2048
#define F_OUT 2048
#define N_EXP 8

#define TM 64
#define TN 64
#define TK 16

// ---------------- routing: sim = |tok @ protos^T|, top-2, softmax ----------------
__global__ __launch_bounds__(256) void route_kernel(
    const float* __restrict__ x,
    const float* __restrict__ protos,
    const int*   __restrict__ scaling,
    int* __restrict__ counts, int* __restrict__ lists, float* __restrict__ coeffs)
{
    const int wave = threadIdx.x >> 6;
    const int lane = threadIdx.x & 63;
    const int token = blockIdx.x * 4 + wave;
    if (token >= T_TOK) return;

    const float* xr = x + (size_t)token * F_IN;
    float s[N_EXP];
    #pragma unroll
    for (int e = 0; e < N_EXP; ++e) s[e] = 0.f;

    for (int c = 0; c < F_IN / 256; ++c) {
        const int off = c * 256 + lane * 4;
        const float4 xv = *(const float4*)(xr + off);
        #pragma unroll
        for (int e = 0; e < N_EXP; ++e) {
            const float4 pv = *(const float4*)(protos + e * F_IN + off);
            s[e] += xv.x * pv.x + xv.y * pv.y + xv.z * pv.z + xv.w * pv.w;
        }
    }
    // 64-lane reduce for all 8 sums
    #pragma unroll
    for (int e = 0; e < N_EXP; ++e) {
        float v = s[e];
        #pragma unroll
        for (int off = 32; off; off >>= 1) v += __shfl_down(v, off, 64);
        s[e] = v;
    }
    if (lane == 0) {
        float v0 = -1.f; int i0 = 0;
        #pragma unroll
        for (int e = 0; e < N_EXP; ++e) {
            const float a = fabsf(s[e]);
            s[e] = a;
            if (a > v0) { v0 = a; i0 = e; }
        }
        float v1 = -1.f; int i1 = 0;
        #pragma unroll
        for (int e = 0; e < N_EXP; ++e) {
            if (e != i0) { const float a = s[e]; if (a > v1) { v1 = a; i1 = e; } }
        }
        const float ex = expf(v1 - v0);           // TEMPERATURE = 1
        const float inv = 1.f / (1.f + ex);
        const float sc = (float)(*scaling);
        const float c0 = sc * inv;
        const float c1 = sc * ex * inv;

        int slot0 = atomicAdd(&counts[i0], 1);
        lists [i0 * T_TOK + slot0] = token;
        coeffs[i0 * T_TOK + slot0] = c0;
        int slot1 = atomicAdd(&counts[i1], 1);
        lists [i1 * T_TOK + slot1] = token;
        coeffs[i1 * T_TOK + slot1] = c1;
    }
}

// ---------------- grouped GEMM: out[tok] += coeff * W[e] @ x[tok] ----------------
__global__ __launch_bounds__(256) void gemm_kernel(
    const float* __restrict__ x,
    const float* __restrict__ W,
    const int*   __restrict__ counts,
    const int*   __restrict__ lists,
    const float* __restrict__ coeffs,
    float* __restrict__ out)
{
    const int e    = blockIdx.x >> 7;     // 8 experts
    const int tile = blockIdx.x & 127;    // up to 128 token tiles of 64
    const int n_e  = counts[e];
    const int tbase = tile * TM;
    if (tbase >= n_e) return;
    const int o0 = blockIdx.y * TN;
    const int rem = n_e - tbase;

    __shared__ float Xs[TK][TM];
    __shared__ float Ws_[TK][TN];
    __shared__ int   toks_s[TM];

    const int tid  = threadIdx.x;
    const int mrow = tid >> 2;          // 0..63 : X-row (token slot) / W-row (out)
    const int kcol = (tid & 3) * 4;     // 0,4,8,12

    int   my_tok = 0;
    float my_cf  = 0.f;
    if (mrow < rem) {
        my_tok = lists [e * T_TOK + tbase + mrow];
        my_cf  = coeffs[e * T_TOK + tbase + mrow];
    }
    if (tid < TM) toks_s[tid] = (tid < rem) ? lists[e * T_TOK + tbase + tid] : -1;

    const float* xrow = x + (size_t)my_tok * F_IN;
    const float* wrow = W + (size_t)e * (F_OUT * (size_t)F_IN) + (size_t)(o0 + mrow) * F_IN;

    const int mb = (tid >> 4) * 4;      // acc row base
    const int nb = (tid & 15) * 4;      // acc col base

    float acc[4][4];
    #pragma unroll
    for (int i = 0; i < 4; ++i)
        #pragma unroll
        for (int j = 0; j < 4; ++j) acc[i][j] = 0.f;

    for (int k0 = 0; k0 < F_IN; k0 += TK) {
        const float4 xv = *(const float4*)(xrow + k0 + kcol);
        const float4 wv = *(const float4*)(wrow + k0 + kcol);
        __syncthreads();
        Xs[kcol + 0][mrow] = my_cf * xv.x;
        Xs[kcol + 1][mrow] = my_cf * xv.y;
        Xs[kcol + 2][mrow] = my_cf * xv.z;
        Xs[kcol + 3][mrow] = my_cf * xv.w;
        Ws_[kcol + 0][mrow] = wv.x;
        Ws_[kcol + 1][mrow] = wv.y;
        Ws_[kcol + 2][mrow] = wv.z;
        Ws_[kcol + 3][mrow] = wv.w;
        __syncthreads();
        #pragma unroll
        for (int k = 0; k < TK; ++k) {
            const float4 a = *(const float4*)&Xs[k][mb];
            const float4 b = *(const float4*)&Ws_[k][nb];
            acc[0][0] += a.x * b.x; acc[0][1] += a.x * b.y; acc[0][2] += a.x * b.z; acc[0][3] += a.x * b.w;
            acc[1][0] += a.y * b.x; acc[1][1] += a.y * b.y; acc[1][2] += a.y * b.z; acc[1][3] += a.y * b.w;
            acc[2][0] += a.z * b.x; acc[2][1] += a.z * b.y; acc[2][2] += a.z * b.z; acc[2][3] += a.z * b.w;
            acc[3][0] += a.w * b.x; acc[3][1] += a.w * b.y; acc[3][2] += a.w * b.z; acc[3][3] += a.w * b.w;
        }
    }

    #pragma unroll
    for (int i = 0; i < 4; ++i) {
        const int tok = toks_s[mb + i];
        if (tok >= 0) {
            float* orow = out + (size_t)tok * F_OUT + o0 + nb;
            #pragma unroll
            for (int j = 0; j < 4; ++j) atomicAdd(&orow[j], acc[i][j]);
        }
    }
}

extern "C" void kernel_launch(void* const* d_in, const int* in_sizes, int n_in,
                              void* d_out, int out_size, void* d_ws, size_t ws_size,
                              hipStream_t stream) {
    const float* x      = (const float*)d_in[0];
    const float* protos = (const float*)d_in[1];
    const float* W      = (const float*)d_in[2];
    const int*   scal   = (const int*)d_in[3];
    float* out = (float*)d_out;

    int*   counts = (int*)d_ws;
    int*   lists  = (int*)((char*)d_ws + 1024);
    float* coeffs = (float*)((char*)d_ws + 1024 + (size_t)N_EXP * T_TOK * 4);

    hipMemsetAsync(counts, 0, N_EXP * sizeof(int), stream);
    hipMemsetAsync(d_out, 0, (size_t)out_size * sizeof(float), stream);

    route_kernel<<<T_TOK / 4, 256, 0, stream>>>(x, protos, scal, counts, lists, coeffs);

    dim3 grid(N_EXP * 128, F_OUT / TN);
    gemm_kernel<<<grid, 256, 0, stream>>>(x, W, counts, lists, coeffs, out);
}

// Round 2
// 647.114 us; speedup vs baseline: 3.8622x; 3.8622x over previous
//
#include <hip/hip_runtime.h>

#define T_TOK 8192
#define F_IN  2048
#define F_OUT 2048
#define N_EXP 8

typedef __attribute__((ext_vector_type(8))) short          short8;   // 8 bf16 = 4 VGPR
typedef __attribute__((ext_vector_type(4))) float          f32x4;
typedef __attribute__((ext_vector_type(8))) unsigned short ushort8;

#define AS1 __attribute__((address_space(1)))
#define AS3 __attribute__((address_space(3)))
#define GLOAD16(g, l) __builtin_amdgcn_global_load_lds((const AS1 unsigned int*)(g), \
                                                       (AS3 unsigned int*)(l), 16, 0, 0)

__device__ inline unsigned short f2bf(float f) {   // round-to-nearest-even
    unsigned u = __float_as_uint(f);
    u += 0x7FFFu + ((u >> 16) & 1u);
    return (unsigned short)(u >> 16);
}

// ---------------- fp32 -> bf16 bulk convert (8 elems/thread) ----------------
__global__ __launch_bounds__(256) void cvt_kernel(const float* __restrict__ in,
                                                  unsigned short* __restrict__ out, int n8) {
    for (int i = blockIdx.x * 256 + threadIdx.x; i < n8; i += gridDim.x * 256) {
        const float4 a = ((const float4*)in)[i * 2 + 0];
        const float4 b = ((const float4*)in)[i * 2 + 1];
        ushort8 v;
        v[0] = f2bf(a.x); v[1] = f2bf(a.y); v[2] = f2bf(a.z); v[3] = f2bf(a.w);
        v[4] = f2bf(b.x); v[5] = f2bf(b.y); v[6] = f2bf(b.z); v[7] = f2bf(b.w);
        ((ushort8*)out)[i] = v;
    }
}

// ---------------- routing: |tok @ protos^T|, top-2, softmax ----------------
__global__ __launch_bounds__(256) void route_kernel(
    const float* __restrict__ x, const float* __restrict__ protos,
    const int* __restrict__ scaling,
    int* __restrict__ counts, int* __restrict__ lists, float* __restrict__ coeffs)
{
    const int wave = threadIdx.x >> 6;
    const int lane = threadIdx.x & 63;
    const int token = blockIdx.x * 4 + wave;
    if (token >= T_TOK) return;

    const float* xr = x + (size_t)token * F_IN;
    float s[N_EXP];
    #pragma unroll
    for (int e = 0; e < N_EXP; ++e) s[e] = 0.f;

    for (int c = 0; c < F_IN / 256; ++c) {
        const int off = c * 256 + lane * 4;
        const float4 xv = *(const float4*)(xr + off);
        #pragma unroll
        for (int e = 0; e < N_EXP; ++e) {
            const float4 pv = *(const float4*)(protos + e * F_IN + off);
            s[e] += xv.x * pv.x + xv.y * pv.y + xv.z * pv.z + xv.w * pv.w;
        }
    }
    #pragma unroll
    for (int e = 0; e < N_EXP; ++e) {
        float v = s[e];
        #pragma unroll
        for (int off = 32; off; off >>= 1) v += __shfl_down(v, off, 64);
        s[e] = v;
    }
    if (lane == 0) {
        float v0 = -1.f; int i0 = 0;
        #pragma unroll
        for (int e = 0; e < N_EXP; ++e) {
            const float a = fabsf(s[e]); s[e] = a;
            if (a > v0) { v0 = a; i0 = e; }
        }
        float v1 = -1.f; int i1 = 0;
        #pragma unroll
        for (int e = 0; e < N_EXP; ++e)
            if (e != i0) { const float a = s[e]; if (a > v1) { v1 = a; i1 = e; } }
        const float ex  = expf(v1 - v0);
        const float inv = 1.f / (1.f + ex);
        const float sc  = (float)(*scaling);
        int slot0 = atomicAdd(&counts[i0], 1);
        lists [i0 * T_TOK + slot0] = token;
        coeffs[i0 * T_TOK + slot0] = sc * inv;
        int slot1 = atomicAdd(&counts[i1], 1);
        lists [i1 * T_TOK + slot1] = token;
        coeffs[i1 * T_TOK + slot1] = sc * ex * inv;
    }
}

// ---------------- grouped bf16 MFMA GEMM (m97 structure) ----------------
// out[tok, o0:o0+128] += coeff * ( X_tile[128 x 2048] @ W_e[o, :]^T )
__global__ __launch_bounds__(256) void gemm_kernel(
    const unsigned short* __restrict__ xb,   // bf16 (T_TOK, F_IN)
    const unsigned short* __restrict__ Wb,   // bf16 (E, F_OUT, F_IN)
    const int* __restrict__ counts, const int* __restrict__ lists,
    const float* __restrict__ coeffs, float* __restrict__ out)
{
    const int e     = blockIdx.x >> 6;       // 8 experts x 64 row-tiles
    const int tile  = blockIdx.x & 63;
    const int n_e   = counts[e];
    const int tbase = tile * 128;
    if (tbase >= n_e) return;
    const int rem = n_e - tbase;
    const int o0  = blockIdx.y * 128;

    __shared__ __align__(16) unsigned short As[128 * 32];  // [row][k] 64B rows
    __shared__ __align__(16) unsigned short Bs[128 * 32];
    __shared__ int   toks_s[128];
    __shared__ float cf_s[128];

    const int tid  = threadIdx.x;
    const int lane = tid & 63;
    const int w    = tid >> 6;
    const int wr   = w >> 1, wc = w & 1;

    if (tid < 128) {
        const int s = tbase + tid;
        const bool v = (tid < rem);
        toks_s[tid] = v ? lists [e * T_TOK + s] : 0;
        cf_s[tid]   = v ? coeffs[e * T_TOK + s] : 0.f;
    }
    __syncthreads();

    // staging addresses: thread covers rows {w*16+lane/4, +64} at k-chunk (lane&3)*8
    const int ldrow = w * 16 + (lane >> 2);
    const int kcol8 = (lane & 3) * 8;
    const unsigned short* gA0 = xb + (size_t)toks_s[ldrow]      * F_IN + kcol8;
    const unsigned short* gA1 = xb + (size_t)toks_s[ldrow + 64] * F_IN + kcol8;
    const unsigned short* gB0 = Wb + ((size_t)e * F_OUT + o0 + ldrow)      * (size_t)F_IN + kcol8;
    const unsigned short* gB1 = Wb + ((size_t)e * F_OUT + o0 + ldrow + 64) * (size_t)F_IN + kcol8;
    unsigned short* lA0 = As + w * 512;            // wave-uniform LDS bases
    unsigned short* lA1 = As + 2048 + w * 512;
    unsigned short* lB0 = Bs + w * 512;
    unsigned short* lB1 = Bs + 2048 + w * 512;

    // fragment read addresses
    const int arow = wr * 64 + (lane & 15);
    const int brow = wc * 64 + (lane & 15);
    const int koff = (lane >> 4) * 8;

    f32x4 acc[4][4] = {};

    for (int k0 = 0; k0 < F_IN; k0 += 32) {
        __syncthreads();                     // previous MFMA reads complete
        GLOAD16(gA0, lA0); GLOAD16(gA1, lA1);
        GLOAD16(gB0, lB0); GLOAD16(gB1, lB1);
        gA0 += 32; gA1 += 32; gB0 += 32; gB1 += 32;
        __syncthreads();                     // staged data visible (vmcnt drained)

        short8 a[4], b[4];
        #pragma unroll
        for (int m = 0; m < 4; ++m)
            a[m] = *(const short8*)(As + (arow + m * 16) * 32 + koff);
        #pragma unroll
        for (int n = 0; n < 4; ++n)
            b[n] = *(const short8*)(Bs + (brow + n * 16) * 32 + koff);
        #pragma unroll
        for (int m = 0; m < 4; ++m)
            #pragma unroll
            for (int n = 0; n < 4; ++n)
                acc[m][n] = __builtin_amdgcn_mfma_f32_16x16x32_bf16(a[m], b[n], acc[m][n], 0, 0, 0);
    }

    // epilogue: C/D layout col=lane&15, row=(lane>>4)*4+reg
    const int rbase = wr * 64 + (lane >> 4) * 4;
    const int cbase = o0 + wc * 64 + (lane & 15);
    #pragma unroll
    for (int m = 0; m < 4; ++m) {
        #pragma unroll
        for (int r = 0; r < 4; ++r) {
            const int slot = rbase + m * 16 + r;
            if (slot < rem) {
                const int   tok = toks_s[slot];
                const float cf  = cf_s[slot];
                float* orow = out + (size_t)tok * F_OUT + cbase;
                #pragma unroll
                for (int n = 0; n < 4; ++n)
                    atomicAdd(&orow[n * 16], cf * acc[m][n][r]);
            }
        }
    }
}

extern "C" void kernel_launch(void* const* d_in, const int* in_sizes, int n_in,
                              void* d_out, int out_size, void* d_ws, size_t ws_size,
                              hipStream_t stream) {
    const float* x      = (const float*)d_in[0];
    const float* protos = (const float*)d_in[1];
    const float* W      = (const float*)d_in[2];
    const int*   scal   = (const int*)d_in[3];
    float* out = (float*)d_out;

    char* ws = (char*)d_ws;
    int*            counts = (int*)ws;                                   // 32 B
    int*            lists  = (int*)(ws + 1024);                          // 256 KB
    float*          coeffs = (float*)(ws + 1024 + (size_t)N_EXP * T_TOK * 4);
    unsigned short* xb     = (unsigned short*)(ws + (4u << 20));                   // 32 MB
    unsigned short* Wb     = (unsigned short*)(ws + (4u << 20) + (size_t)T_TOK * F_IN * 2); // 64 MB

    hipMemsetAsync(counts, 0, N_EXP * sizeof(int), stream);
    hipMemsetAsync(d_out, 0, (size_t)out_size * sizeof(float), stream);

    cvt_kernel<<<1024, 256, 0, stream>>>(x, xb, T_TOK * F_IN / 8);
    cvt_kernel<<<2048, 256, 0, stream>>>(W, Wb, N_EXP * F_OUT * F_IN / 8);
    route_kernel<<<T_TOK / 4, 256, 0, stream>>>(x, protos, scal, counts, lists, coeffs);

    dim3 grid(N_EXP * 64, F_OUT / 128);
    gemm_kernel<<<grid, 256, 0, stream>>>(xb, Wb, counts, lists, coeffs, out);
}